// Round 1
// baseline (230.172 us; speedup 1.0000x reference)
//
#include <hip/hip_runtime.h>
#include <hip/hip_bf16.h>

// Problem constants (B=4, S=2048, D=1024, fp32 in/out)
#define BB 4
#define SS 2048
#define DD 1024

using f32x4  = __attribute__((ext_vector_type(4))) float;
using i32x4  = __attribute__((ext_vector_type(4))) int;
using i32x8  = __attribute__((ext_vector_type(8))) int;

struct f8_t { unsigned char b; };

// async global->LDS, 16B per lane. LDS dest = wave-uniform base + lane*16.
__device__ __forceinline__ void gld16(const void* g, void* l) {
    __builtin_amdgcn_global_load_lds(
        (const __attribute__((address_space(1))) void*)(g),
        (__attribute__((address_space(3))) void*)(l),
        16, 0, 0);
}

__device__ __forceinline__ void store1(float* p, float v) { *p = v; }
__device__ __forceinline__ void store1(f8_t* p, float v)  {
    p->b = (unsigned char)(__builtin_amdgcn_cvt_pk_fp8_f32(v, v, 0, false) & 0xff);
}

// ---------------------------------------------------------------------------
// x: fp32 -> fp8(e4m3), 8 elems/thread
// ---------------------------------------------------------------------------
__global__ void cvt_x_kernel(const float* __restrict__ x, unsigned char* __restrict__ x8, int n8) {
    int i = blockIdx.x * blockDim.x + threadIdx.x;
    if (i >= n8) return;
    float4 a = ((const float4*)x)[2 * i];
    float4 b = ((const float4*)x)[2 * i + 1];
    int lo = __builtin_amdgcn_cvt_pk_fp8_f32(a.x, a.y, 0, false);
    lo     = __builtin_amdgcn_cvt_pk_fp8_f32(a.z, a.w, lo, true);
    int hi = __builtin_amdgcn_cvt_pk_fp8_f32(b.x, b.y, 0, false);
    hi     = __builtin_amdgcn_cvt_pk_fp8_f32(b.z, b.w, hi, true);
    ((int2*)x8)[i] = make_int2(lo, hi);
}

// Wq,Wk,Wv -> fp8 contiguous. n8 = nw/8.
__global__ void cvt_w_kernel(const float* __restrict__ Wq, const float* __restrict__ Wk,
                             const float* __restrict__ Wv, unsigned char* __restrict__ w8, int n8) {
    int i = blockIdx.x * blockDim.x + threadIdx.x;
    int seg = i / n8;            // wave-uniform (n8 % 256 == 0)
    int j = i - seg * n8;
    const float* src = (seg == 0) ? Wq : (seg == 1) ? Wk : Wv;
    float4 a = ((const float4*)src)[2 * j];
    float4 b = ((const float4*)src)[2 * j + 1];
    int lo = __builtin_amdgcn_cvt_pk_fp8_f32(a.x, a.y, 0, false);
    lo     = __builtin_amdgcn_cvt_pk_fp8_f32(a.z, a.w, lo, true);
    int hi = __builtin_amdgcn_cvt_pk_fp8_f32(b.x, b.y, 0, false);
    hi     = __builtin_amdgcn_cvt_pk_fp8_f32(b.z, b.w, hi, true);
    ((int2*)(w8 + (size_t)seg * n8 * 8))[j] = make_int2(lo, hi);
}

// ---------------------------------------------------------------------------
// xsum[b][d] = sum_s x[b][s][d]  (fp32, exact). atomics over s-chunks.
// grid (16, 16): x = (b*4+dchunk), y = schunk of 128.
// ---------------------------------------------------------------------------
__global__ void xsum_kernel(const float* __restrict__ x, float* __restrict__ xsum) {
    int bd = blockIdx.x;
    int b  = bd >> 2, dc = bd & 3;
    int d  = dc * 256 + threadIdx.x;
    int s0 = blockIdx.y * 128;
    const float* p = x + ((size_t)b * SS + s0) * DD + d;
    float acc = 0.f;
    for (int i = 0; i < 128; ++i) acc += p[(size_t)i * DD];
    atomicAdd(&xsum[b * DD + d], acc);
}

// colsumV[b][c] = sum_d xsum[b][d] * Wv[c][d]   (one wave per output)
__global__ void colsumv_kernel(const float* __restrict__ Wv, const float* __restrict__ xsum,
                               float* __restrict__ colsum) {
    int idx  = blockIdx.x * 4 + (threadIdx.x >> 6);   // 0..4095
    int b    = idx >> 10, c = idx & 1023;
    int lane = threadIdx.x & 63;
    const float* wr = Wv + (size_t)c * DD;
    const float* xs = xsum + b * DD;
    float acc = 0.f;
#pragma unroll 4
    for (int d = lane; d < DD; d += 64) acc += wr[d] * xs[d];
#pragma unroll
    for (int off = 32; off; off >>= 1) acc += __shfl_xor(acc, off);
    if (lane == 0) colsum[idx] = acc;
}

// ---------------------------------------------------------------------------
// fp8 (e4m3) NT GEMM via MX-scaled MFMA 16x16x128.
// 256x128 tile, BK=128, 512 threads (8 waves, 4M x 2N), per-wave 64x64 out.
// Double-buffered LDS, 8-phase-style schedule: per K-tile 3 phases of
// {ds_read frags || issue global_load_lds prefetch -> s_barrier -> lgkmcnt(0)
//  -> setprio(1) MFMA cluster setprio(0) -> s_barrier}; vmcnt drained ONCE per
// K-tile at the boundary (counted-wait pipeline, T3+T4), not after issue.
// XOR-8 LDS swizzle on the staging source (T2). setprio around MFMA (T5).
// Epilogue modes:
//   0: plain store CT              (QK projection, fp8 out)
//   1: col-batch-split fp8 store   (V^T)
//   2: scores: t=exp(acc*qmask/32)-1; store fp8 512t; atomicAdd row sums of t
//   3: PV: out = (acc + colsumV[d]) / (2048 + rsum[q]), fp32; A-scale 2^-9
// ---------------------------------------------------------------------------
template <int MODE, typename CT>
__global__ __launch_bounds__(512, 2) void gemm_f8(
    const unsigned char* __restrict__ A, const unsigned char* __restrict__ B,
    CT* __restrict__ C, int M, int N, int K,
    long batchA, long batchB, long batchC,
    int ldc, int col_shift, long cstride,
    const float* __restrict__ qmask, float* __restrict__ rsum,
    const float* __restrict__ colsum) {
    constexpr int BM = 256, BN = 128, BK = 128;
    constexpr int SCALE_A = (MODE == 3) ? 118 : 127;   // 2^-9 un-scales T' = 512 t
    __shared__ __attribute__((aligned(16))) unsigned char As[2][BM * BK];  // 64 KB
    __shared__ __attribute__((aligned(16))) unsigned char Bs[2][BN * BK];  // 32 KB

    const int tid  = threadIdx.x;
    const int lane = tid & 63;
    const int wv   = tid >> 6;        // 0..7
    const int l16  = lane & 15;
    const int quad = lane >> 4;
    const int wm   = wv >> 1;         // 0..3 : 64-row band
    const int wn   = wv & 1;          // 0..1 : 64-col band

    const int m0 = blockIdx.y * BM;
    const int n0 = blockIdx.x * BN;
    const long z = blockIdx.z;
    const unsigned char* Ab = A + z * batchA;
    const unsigned char* Bb = B + z * batchB;

    const int cbase = 2 * quad;       // chunk pair base for frag reads

    f32x4 acc[4][4] = {};

    // stage round j of the A tile (j=0..3) / B tile (j=0..1) for K-offset kt
    // into buffer `buf`. Source address carries the XOR-8 swizzle; LDS dest is
    // linear (global_load_lds writes base + lane*16).
#define STAGE_A(buf, kt, j) do {                                              \
        int slot_ = (j) * 512 + tid;                                          \
        int r_ = slot_ >> 3;                                                  \
        int c_ = (slot_ & 7) ^ (r_ & 7);                                      \
        gld16(Ab + (size_t)(m0 + r_) * K + ((kt) + c_ * 16),                  \
              &As[buf][((j) * 512 + wv * 64) * 16]);                          \
    } while (0)
#define STAGE_B(buf, kt, j) do {                                              \
        int slot_ = (j) * 512 + tid;                                          \
        int r_ = slot_ >> 3;                                                  \
        int c_ = (slot_ & 7) ^ (r_ & 7);                                      \
        gld16(Bb + (size_t)(n0 + r_) * K + ((kt) + c_ * 16),                  \
              &Bs[buf][((j) * 512 + wv * 64) * 16]);                          \
    } while (0)
    // read one 16x128 fragment (32 B/lane, two swizzled 16B chunks) at row r
#define RDFRAG(f, base, r) do {                                               \
        int cc_ = cbase ^ ((r) & 7);                                          \
        i32x4 p0_ = *(const i32x4*)((base) + (r) * 128 + cc_ * 16);           \
        i32x4 p1_ = *(const i32x4*)((base) + (r) * 128 + (cc_ ^ 1) * 16);     \
        f[0]=p0_[0]; f[1]=p0_[1]; f[2]=p0_[2]; f[3]=p0_[3];                   \
        f[4]=p1_[0]; f[5]=p1_[1]; f[6]=p1_[2]; f[7]=p1_[3];                   \
    } while (0)
#define MFMA(d, a, b) \
        d = __builtin_amdgcn_mfma_scale_f32_16x16x128_f8f6f4(a, b, d, 0, 0, 0, SCALE_A, 0, 127)

    // ---- prologue: stage K-tile 0 into buffer 0, full drain once ----------
    STAGE_A(0, 0, 0); STAGE_A(0, 0, 1); STAGE_A(0, 0, 2); STAGE_A(0, 0, 3);
    STAGE_B(0, 0, 0); STAGE_B(0, 0, 1);
    asm volatile("s_waitcnt vmcnt(0)" ::: "memory");
    __builtin_amdgcn_s_barrier();

    const int NT = K / BK;
    for (int t = 0; t < NT; ++t) {
        const int cur = t & 1;
        const int nxt = cur ^ 1;
        const unsigned char* Ac = &As[cur][0];
        const unsigned char* Bc = &Bs[cur][0];
        const int ktn = (t + 1) * BK;
        const bool pf = (t + 1 < NT);

        i32x8 a0, a1, a2, a3, b0, b1, b2, b3;

        // ---- phase 1: frags m0,m1 + n0,n1; prefetch 3 rounds; mfma m01xn01
        RDFRAG(a0, Ac, wm * 64 +  0 + l16);
        RDFRAG(a1, Ac, wm * 64 + 16 + l16);
        RDFRAG(b0, Bc, wn * 64 +  0 + l16);
        RDFRAG(b1, Bc, wn * 64 + 16 + l16);
        if (pf) { STAGE_A(nxt, ktn, 0); STAGE_A(nxt, ktn, 1); STAGE_A(nxt, ktn, 2); }
        __builtin_amdgcn_s_barrier();
        asm volatile("s_waitcnt lgkmcnt(0)" ::: "memory");
        __builtin_amdgcn_sched_barrier(0);
        __builtin_amdgcn_s_setprio(1);
        MFMA(acc[0][0], a0, b0); MFMA(acc[0][1], a0, b1);
        MFMA(acc[1][0], a1, b0); MFMA(acc[1][1], a1, b1);
        __builtin_amdgcn_s_setprio(0);
        __builtin_amdgcn_s_barrier();

        // ---- phase 2: frags n2,n3; prefetch 3 rounds; mfma m01xn23 --------
        RDFRAG(b2, Bc, wn * 64 + 32 + l16);
        RDFRAG(b3, Bc, wn * 64 + 48 + l16);
        if (pf) { STAGE_A(nxt, ktn, 3); STAGE_B(nxt, ktn, 0); STAGE_B(nxt, ktn, 1); }
        __builtin_amdgcn_s_barrier();
        asm volatile("s_waitcnt lgkmcnt(0)" ::: "memory");
        __builtin_amdgcn_sched_barrier(0);
        __builtin_amdgcn_s_setprio(1);
        MFMA(acc[0][2], a0, b2); MFMA(acc[0][3], a0, b3);
        MFMA(acc[1][2], a1, b2); MFMA(acc[1][3], a1, b3);
        __builtin_amdgcn_s_setprio(0);
        __builtin_amdgcn_s_barrier();

        // ---- phase 3: frags m2,m3; mfma m23xn23 then m23xn01; boundary ----
        RDFRAG(a2, Ac, wm * 64 + 32 + l16);
        RDFRAG(a3, Ac, wm * 64 + 48 + l16);
        __builtin_amdgcn_s_barrier();
        asm volatile("s_waitcnt lgkmcnt(0)" ::: "memory");
        __builtin_amdgcn_sched_barrier(0);
        __builtin_amdgcn_s_setprio(1);
        MFMA(acc[2][2], a2, b2); MFMA(acc[2][3], a2, b3);
        MFMA(acc[3][2], a3, b2); MFMA(acc[3][3], a3, b3);
        MFMA(acc[2][0], a2, b0); MFMA(acc[2][1], a2, b1);
        MFMA(acc[3][0], a3, b0); MFMA(acc[3][1], a3, b1);
        __builtin_amdgcn_s_setprio(0);
        // K-tile boundary: drain this wave's prefetch (issued ~2 phases ago,
        // mostly landed), then barrier -> buf[nxt] is consistent chip-wide.
        asm volatile("s_waitcnt vmcnt(0)" ::: "memory");
        __builtin_amdgcn_s_barrier();
    }
#undef STAGE_A
#undef STAGE_B
#undef RDFRAG
#undef MFMA

    // ---------------- epilogue (C/D layout: col=lane&15, row=quad*4+reg) ----
    CT* Cb = C + z * batchC;

    if constexpr (MODE == 0) {
#pragma unroll
        for (int mi = 0; mi < 4; ++mi)
#pragma unroll
            for (int ni = 0; ni < 4; ++ni) {
                int colg = n0 + wn * 64 + ni * 16 + l16;
#pragma unroll
                for (int r = 0; r < 4; ++r) {
                    int rowg = m0 + wm * 64 + mi * 16 + quad * 4 + r;
                    store1(Cb + (size_t)rowg * ldc + colg, acc[mi][ni][r]);
                }
            }
    } else if constexpr (MODE == 1) {
#pragma unroll
        for (int mi = 0; mi < 4; ++mi)
#pragma unroll
            for (int ni = 0; ni < 4; ++ni) {
                int colg = n0 + wn * 64 + ni * 16 + l16;
                int cb   = colg >> col_shift;
                int ccol = colg - (cb << col_shift);
#pragma unroll
                for (int r = 0; r < 4; ++r) {
                    int rowg = m0 + wm * 64 + mi * 16 + quad * 4 + r;
                    store1(Cb + (long)cb * cstride + (size_t)rowg * ldc + ccol, acc[mi][ni][r]);
                }
            }
    } else if constexpr (MODE == 2) {
        const float* qm = qmask + (z << 11);
        float* rs = rsum + (z << 11);
#pragma unroll
        for (int mi = 0; mi < 4; ++mi) {
#pragma unroll
            for (int r = 0; r < 4; ++r) {
                int rowg = m0 + wm * 64 + mi * 16 + quad * 4 + r;
                float fac = qm[rowg] * 0.03125f;     // q_mask / sqrt(1024)
                float part = 0.f;
#pragma unroll
                for (int ni = 0; ni < 4; ++ni) {
                    int colg = n0 + wn * 64 + ni * 16 + l16;
                    float t = __expf(acc[mi][ni][r] * fac) - 1.0f;
                    part += t;
                    store1(Cb + (size_t)rowg * ldc + colg, t * 512.0f);
                }
                // reduce over the 16 lanes sharing this row (l16 group)
                part += __shfl_xor(part, 1);
                part += __shfl_xor(part, 2);
                part += __shfl_xor(part, 4);
                part += __shfl_xor(part, 8);
                if (l16 == 0) atomicAdd(&rs[rowg], part);
            }
        }
    } else {  // MODE == 3
        const float* rs = rsum + (z << 11);
        const float* cs = colsum + (z << 10);
#pragma unroll
        for (int mi = 0; mi < 4; ++mi) {
#pragma unroll
            for (int r = 0; r < 4; ++r) {
                int rowg = m0 + wm * 64 + mi * 16 + quad * 4 + r;
                float inv = 1.0f / (2048.0f + rs[rowg]);
#pragma unroll
                for (int ni = 0; ni < 4; ++ni) {
                    int colg = n0 + wn * 64 + ni * 16 + l16;
                    store1(Cb + (size_t)rowg * ldc + colg, (acc[mi][ni][r] + cs[colg]) * inv);
                }
            }
        }
    }
}

// ---------------------------------------------------------------------------
extern "C" void kernel_launch(void* const* d_in, const int* in_sizes, int n_in,
                              void* d_out, int out_size, void* d_ws, size_t ws_size,
                              hipStream_t stream) {
    const float* x     = (const float*)d_in[0];
    const float* Wq    = (const float*)d_in[1];
    const float* Wk    = (const float*)d_in[2];
    const float* Wv    = (const float*)d_in[3];
    const float* qmask = (const float*)d_in[4];
    float* out = (float*)d_out;

    const long nx = (long)BB * SS * DD;   // 8,388,608
    const long nw = (long)DD * DD;        // 1,048,576

    unsigned char* ws  = (unsigned char*)d_ws;
    unsigned char* x8  = ws;                          // x fp8         8.4 MB
    unsigned char* w8  = x8 + nx;                     // Wq,Wk,Wv fp8  3 MB
    unsigned char* qk8 = w8 + 3 * nw;                 // Q,K fp8       16.8 MB
    unsigned char* vt8 = qk8 + 2 * nx;                // V^T fp8 (B,D,S) 8.4 MB
    unsigned char* t8  = vt8 + nx;                    // T = 512(exp-1) fp8 (B,S,S) 16.8 MB
    float* xsum   = (float*)(t8 + (long)BB * SS * SS);// (B,D) 16 KB
    float* rs     = xsum + BB * DD;                   // (B,S) 32 KB  (Σt per row)
    float* colsum = rs + BB * SS;                     // (B,D) 16 KB

    // 0. zero the accumulators (xsum and rs are adjacent)
    hipMemsetAsync(xsum, 0, (size_t)(BB * DD + BB * SS) * sizeof(float), stream);

    // 1. conversions + exact colsum(V) path
    cvt_x_kernel<<<dim3((int)(nx / 8 / 256)), dim3(256), 0, stream>>>(x, x8, (int)(nx / 8));
    cvt_w_kernel<<<dim3((int)(3 * nw / 8 / 256)), dim3(256), 0, stream>>>(Wq, Wk, Wv, w8, (int)(nw / 8));
    xsum_kernel<<<dim3(16, 16), dim3(256), 0, stream>>>(x, xsum);
    colsumv_kernel<<<dim3(1024), dim3(256), 0, stream>>>(Wv, xsum, colsum);

    // 2. Q = x@Wq^T, K = x@Wk^T  (fp8 MX GEMM, z=2, fp8 out)  grid 8x32x2
    gemm_f8<0, f8_t><<<dim3(DD / 128, (BB * SS) / 256, 2), 512, 0, stream>>>(
        x8, w8, (f8_t*)qk8, BB * SS, DD, DD, 0, nw, nx, DD, 31, 0, nullptr, nullptr, nullptr);

    // 3. V^T = Wv @ x^T -> (B, D, S) fp8, col-batch-split store  grid 64x4
    gemm_f8<1, f8_t><<<dim3((BB * SS) / 128, DD / 256, 1), 512, 0, stream>>>(
        w8 + 2 * nw, x8, (f8_t*)vt8, DD, BB * SS, DD, 0, 0, 0, SS, 11, (long)DD * SS,
        nullptr, nullptr, nullptr);

    // 4. T = exp(mask*scores)-1 (x512, fp8) + row sums of t (atomics)  grid 16x8x4
    gemm_f8<2, f8_t><<<dim3(SS / 128, SS / 256, BB), 512, 0, stream>>>(
        qk8, qk8 + nx, (f8_t*)t8, SS, SS, DD, (long)SS * DD, (long)SS * DD, (long)SS * SS,
        SS, 31, 0, qmask, rs, nullptr);

    // 5. out = (T@V * 2^-9 + colsumV) / (2048 + rowsum_t), fp32  grid 8x8x4
    gemm_f8<3, float><<<dim3(DD / 128, SS / 256, BB), 512, 0, stream>>>(
        t8, vt8, out, SS, DD, SS, (long)SS * SS, (long)DD * SS, (long)SS * DD,
        DD, 31, 0, nullptr, rs, colsum);
}

// Round 2
// 221.277 us; speedup vs baseline: 1.0402x; 1.0402x over previous
//
#include <hip/hip_runtime.h>
#include <hip/hip_bf16.h>

// Problem constants (B=4, S=2048, D=1024, fp32 in/out)
#define BB 4
#define SS 2048
#define DD 1024

using f32x4  = __attribute__((ext_vector_type(4))) float;
using i32x4  = __attribute__((ext_vector_type(4))) int;
using i32x8  = __attribute__((ext_vector_type(8))) int;

struct f8_t { unsigned char b; };

// async global->LDS, 16B per lane. LDS dest = wave-uniform base + lane*16.
__device__ __forceinline__ void gld16(const void* g, void* l) {
    __builtin_amdgcn_global_load_lds(
        (const __attribute__((address_space(1))) void*)(g),
        (__attribute__((address_space(3))) void*)(l),
        16, 0, 0);
}

__device__ __forceinline__ void store1(float* p, float v) { *p = v; }
__device__ __forceinline__ void store1(f8_t* p, float v)  {
    p->b = (unsigned char)(__builtin_amdgcn_cvt_pk_fp8_f32(v, v, 0, false) & 0xff);
}

// ---------------------------------------------------------------------------
// x: fp32 -> fp8(e4m3), 8 elems/thread
// ---------------------------------------------------------------------------
__global__ void cvt_x_kernel(const float* __restrict__ x, unsigned char* __restrict__ x8, int n8) {
    int i = blockIdx.x * blockDim.x + threadIdx.x;
    if (i >= n8) return;
    float4 a = ((const float4*)x)[2 * i];
    float4 b = ((const float4*)x)[2 * i + 1];
    int lo = __builtin_amdgcn_cvt_pk_fp8_f32(a.x, a.y, 0, false);
    lo     = __builtin_amdgcn_cvt_pk_fp8_f32(a.z, a.w, lo, true);
    int hi = __builtin_amdgcn_cvt_pk_fp8_f32(b.x, b.y, 0, false);
    hi     = __builtin_amdgcn_cvt_pk_fp8_f32(b.z, b.w, hi, true);
    ((int2*)x8)[i] = make_int2(lo, hi);
}

// Wq,Wk,Wv -> fp8 contiguous. n8 = nw/8.
__global__ void cvt_w_kernel(const float* __restrict__ Wq, const float* __restrict__ Wk,
                             const float* __restrict__ Wv, unsigned char* __restrict__ w8, int n8) {
    int i = blockIdx.x * blockDim.x + threadIdx.x;
    int seg = i / n8;            // wave-uniform (n8 % 256 == 0)
    int j = i - seg * n8;
    const float* src = (seg == 0) ? Wq : (seg == 1) ? Wk : Wv;
    float4 a = ((const float4*)src)[2 * j];
    float4 b = ((const float4*)src)[2 * j + 1];
    int lo = __builtin_amdgcn_cvt_pk_fp8_f32(a.x, a.y, 0, false);
    lo     = __builtin_amdgcn_cvt_pk_fp8_f32(a.z, a.w, lo, true);
    int hi = __builtin_amdgcn_cvt_pk_fp8_f32(b.x, b.y, 0, false);
    hi     = __builtin_amdgcn_cvt_pk_fp8_f32(b.z, b.w, hi, true);
    ((int2*)(w8 + (size_t)seg * n8 * 8))[j] = make_int2(lo, hi);
}

// ---------------------------------------------------------------------------
// xsum[b][d] = sum_s x[b][s][d]  (fp32, exact). atomics over s-chunks.
// ---------------------------------------------------------------------------
__global__ void xsum_kernel(const float* __restrict__ x, float* __restrict__ xsum) {
    int bd = blockIdx.x;
    int b  = bd >> 2, dc = bd & 3;
    int d  = dc * 256 + threadIdx.x;
    int s0 = blockIdx.y * 128;
    const float* p = x + ((size_t)b * SS + s0) * DD + d;
    float acc = 0.f;
    for (int i = 0; i < 128; ++i) acc += p[(size_t)i * DD];
    atomicAdd(&xsum[b * DD + d], acc);
}

// colsumV[b][c] = sum_d xsum[b][d] * Wv[c][d]   (one wave per output)
__global__ void colsumv_kernel(const float* __restrict__ Wv, const float* __restrict__ xsum,
                               float* __restrict__ colsum) {
    int idx  = blockIdx.x * 4 + (threadIdx.x >> 6);   // 0..4095
    int b    = idx >> 10, c = idx & 1023;
    int lane = threadIdx.x & 63;
    const float* wr = Wv + (size_t)c * DD;
    const float* xs = xsum + b * DD;
    float acc = 0.f;
#pragma unroll 4
    for (int d = lane; d < DD; d += 64) acc += wr[d] * xs[d];
#pragma unroll
    for (int off = 32; off; off >>= 1) acc += __shfl_xor(acc, off);
    if (lane == 0) colsum[idx] = acc;
}

// ---------------------------------------------------------------------------
// fp8 (e4m3) NT GEMM via MX-scaled MFMA 16x16x128.
// 256x128 tile, BK=128, 512 threads (8 waves, 4M x 2N), per-wave 64x64 out.
// TRIPLE-buffered LDS + counted vmcnt (T3+T4 done right): at iter t we issue
// tile t+2's 6 global_load_lds, compute tile t, then wait vmcnt(6) -- which
// drains only tile t+1's loads, issued a full iteration (~600+ cyc) earlier.
// vmcnt never hits 0 in steady state; ONE raw s_barrier per K-tile; compiler
// manages lgkmcnt for the ds_read->MFMA deps (no inline lgkm asm, rule #18).
// XOR-8 LDS swizzle on the staging source (T2). setprio around compute (T5).
// Bijective XCD swizzle on the x-y plane (T1): all grids divisible by 8.
// Epilogue modes:
//   0: plain store CT              (QK projection, fp8 out)
//   1: col-batch-split fp8 store   (V^T)
//   2: scores: t=exp(acc*qmask/32)-1; store fp8 512t; atomicAdd row sums of t
//   3: PV: out = (acc + colsumV[d]) / (2048 + rsum[q]), fp32; A-scale 2^-9
// ---------------------------------------------------------------------------
template <int MODE, typename CT>
__global__ __launch_bounds__(512, 2) void gemm_f8(
    const unsigned char* __restrict__ A, const unsigned char* __restrict__ B,
    CT* __restrict__ C, int M, int N, int K,
    long batchA, long batchB, long batchC,
    int ldc, int col_shift, long cstride,
    const float* __restrict__ qmask, float* __restrict__ rsum,
    const float* __restrict__ colsum) {
    constexpr int BM = 256, BN = 128, BK = 128;
    constexpr int SCALE_A = (MODE == 3) ? 118 : 127;   // 2^-9 un-scales T' = 512 t
    __shared__ __attribute__((aligned(16))) unsigned char As[3][BM * BK];  // 96 KB
    __shared__ __attribute__((aligned(16))) unsigned char Bs[3][BN * BK];  // 48 KB

    const int tid  = threadIdx.x;
    const int lane = tid & 63;
    const int wv   = tid >> 6;        // 0..7
    const int l16  = lane & 15;
    const int quad = lane >> 4;
    const int wm   = wv >> 1;         // 0..3 : 64-row band
    const int wn   = wv & 1;          // 0..1 : 64-col band

    // T1: bijective XCD-chunked swizzle of the x-y plane (nwg % 8 == 0 for
    // every grid we launch). Blocks landing on one XCD get a contiguous run
    // of work ids -> they share A-panels (runs of gridDim.x) in that XCD's L2.
    const int gx  = gridDim.x;
    const int nwg = gx * gridDim.y;
    const int lin = blockIdx.y * gx + blockIdx.x;
    const int cpx = nwg >> 3;
    const int swz = (lin & 7) * cpx + (lin >> 3);
    const int m0 = (swz / gx) * BM;
    const int n0 = (swz % gx) * BN;
    const long z = blockIdx.z;
    const unsigned char* Ab = A + z * batchA;
    const unsigned char* Bb = B + z * batchB;

    const int cbase = 2 * quad;       // chunk pair base for frag reads

    f32x4 acc[4][4] = {};

    // stage round j of the A tile (j=0..3) / B tile (j=0..1) for K-offset kt
    // into buffer `buf`. Source address carries the XOR-8 swizzle; LDS dest is
    // linear (global_load_lds writes base + lane*16).
#define STAGE_A(buf, kt, j) do {                                              \
        int slot_ = (j) * 512 + tid;                                          \
        int r_ = slot_ >> 3;                                                  \
        int c_ = (slot_ & 7) ^ (r_ & 7);                                      \
        gld16(Ab + (size_t)(m0 + r_) * K + ((kt) + c_ * 16),                  \
              &As[buf][((j) * 512 + wv * 64) * 16]);                          \
    } while (0)
#define STAGE_B(buf, kt, j) do {                                              \
        int slot_ = (j) * 512 + tid;                                          \
        int r_ = slot_ >> 3;                                                  \
        int c_ = (slot_ & 7) ^ (r_ & 7);                                      \
        gld16(Bb + (size_t)(n0 + r_) * K + ((kt) + c_ * 16),                  \
              &Bs[buf][((j) * 512 + wv * 64) * 16]);                          \
    } while (0)
    // read one 16x128 fragment (32 B/lane, two swizzled 16B chunks) at row r
#define RDFRAG(f, base, r) do {                                               \
        int cc_ = cbase ^ ((r) & 7);                                          \
        i32x4 p0_ = *(const i32x4*)((base) + (r) * 128 + cc_ * 16);           \
        i32x4 p1_ = *(const i32x4*)((base) + (r) * 128 + (cc_ ^ 1) * 16);     \
        f[0]=p0_[0]; f[1]=p0_[1]; f[2]=p0_[2]; f[3]=p0_[3];                   \
        f[4]=p1_[0]; f[5]=p1_[1]; f[6]=p1_[2]; f[7]=p1_[3];                   \
    } while (0)
#define MFMA(d, a, b) \
        d = __builtin_amdgcn_mfma_scale_f32_16x16x128_f8f6f4(a, b, d, 0, 0, 0, SCALE_A, 0, 127)

    // ---- prologue: stage K-tiles 0,1 into buffers 0,1; wait only tile 0 ----
    STAGE_A(0, 0, 0); STAGE_A(0, 0, 1); STAGE_A(0, 0, 2); STAGE_A(0, 0, 3);
    STAGE_B(0, 0, 0); STAGE_B(0, 0, 1);
    STAGE_A(1, BK, 0); STAGE_A(1, BK, 1); STAGE_A(1, BK, 2); STAGE_A(1, BK, 3);
    STAGE_B(1, BK, 0); STAGE_B(1, BK, 1);
    asm volatile("s_waitcnt vmcnt(6)" ::: "memory");
    __builtin_amdgcn_s_barrier();
    __builtin_amdgcn_sched_barrier(0);

    const int NT = K / BK;
    int cur = 0;
    for (int t = 0; t < NT; ++t) {
        const unsigned char* Ac = &As[cur][0];
        const unsigned char* Bc = &Bs[cur][0];

        // issue tile t+2's stage into the third buffer (6 loads/thread)
        if (t + 2 < NT) {
            int nb = cur + 2; if (nb >= 3) nb -= 3;
            int ktn = (t + 2) * BK;
            STAGE_A(nb, ktn, 0); STAGE_A(nb, ktn, 1);
            STAGE_A(nb, ktn, 2); STAGE_A(nb, ktn, 3);
            STAGE_B(nb, ktn, 0); STAGE_B(nb, ktn, 1);
        }

        __builtin_amdgcn_s_setprio(1);
        i32x8 a0, a1, a2, a3, b0, b1, b2, b3;
        RDFRAG(b0, Bc, wn * 64 +  0 + l16);
        RDFRAG(b1, Bc, wn * 64 + 16 + l16);
        RDFRAG(b2, Bc, wn * 64 + 32 + l16);
        RDFRAG(b3, Bc, wn * 64 + 48 + l16);
        RDFRAG(a0, Ac, wm * 64 +  0 + l16);
        RDFRAG(a1, Ac, wm * 64 + 16 + l16);
        MFMA(acc[0][0], a0, b0); MFMA(acc[0][1], a0, b1);
        MFMA(acc[0][2], a0, b2); MFMA(acc[0][3], a0, b3);
        MFMA(acc[1][0], a1, b0); MFMA(acc[1][1], a1, b1);
        MFMA(acc[1][2], a1, b2); MFMA(acc[1][3], a1, b3);
        RDFRAG(a2, Ac, wm * 64 + 32 + l16);
        RDFRAG(a3, Ac, wm * 64 + 48 + l16);
        MFMA(acc[2][0], a2, b0); MFMA(acc[2][1], a2, b1);
        MFMA(acc[2][2], a2, b2); MFMA(acc[2][3], a2, b3);
        MFMA(acc[3][0], a3, b0); MFMA(acc[3][1], a3, b1);
        MFMA(acc[3][2], a3, b2); MFMA(acc[3][3], a3, b3);
        __builtin_amdgcn_s_setprio(0);

        // counted wait: drains only tile t+1's loads (issued last iteration).
        if (t + 2 < NT) asm volatile("s_waitcnt vmcnt(6)" ::: "memory");
        else            asm volatile("s_waitcnt vmcnt(0)" ::: "memory");
        __builtin_amdgcn_s_barrier();
        __builtin_amdgcn_sched_barrier(0);
        if (++cur == 3) cur = 0;
    }
#undef STAGE_A
#undef STAGE_B
#undef RDFRAG
#undef MFMA

    // ---------------- epilogue (C/D layout: col=lane&15, row=quad*4+reg) ----
    CT* Cb = C + z * batchC;

    if constexpr (MODE == 0) {
#pragma unroll
        for (int mi = 0; mi < 4; ++mi)
#pragma unroll
            for (int ni = 0; ni < 4; ++ni) {
                int colg = n0 + wn * 64 + ni * 16 + l16;
#pragma unroll
                for (int r = 0; r < 4; ++r) {
                    int rowg = m0 + wm * 64 + mi * 16 + quad * 4 + r;
                    store1(Cb + (size_t)rowg * ldc + colg, acc[mi][ni][r]);
                }
            }
    } else if constexpr (MODE == 1) {
#pragma unroll
        for (int mi = 0; mi < 4; ++mi)
#pragma unroll
            for (int ni = 0; ni < 4; ++ni) {
                int colg = n0 + wn * 64 + ni * 16 + l16;
                int cb   = colg >> col_shift;
                int ccol = colg - (cb << col_shift);
#pragma unroll
                for (int r = 0; r < 4; ++r) {
                    int rowg = m0 + wm * 64 + mi * 16 + quad * 4 + r;
                    store1(Cb + (long)cb * cstride + (size_t)rowg * ldc + ccol, acc[mi][ni][r]);
                }
            }
    } else if constexpr (MODE == 2) {
        const float* qm = qmask + (z << 11);
        float* rs = rsum + (z << 11);
#pragma unroll
        for (int mi = 0; mi < 4; ++mi) {
#pragma unroll
            for (int r = 0; r < 4; ++r) {
                int rowg = m0 + wm * 64 + mi * 16 + quad * 4 + r;
                float fac = qm[rowg] * 0.03125f;     // q_mask / sqrt(1024)
                float part = 0.f;
#pragma unroll
                for (int ni = 0; ni < 4; ++ni) {
                    int colg = n0 + wn * 64 + ni * 16 + l16;
                    float t = __expf(acc[mi][ni][r] * fac) - 1.0f;
                    part += t;
                    store1(Cb + (size_t)rowg * ldc + colg, t * 512.0f);
                }
                // reduce over the 16 lanes sharing this row (l16 group)
                part += __shfl_xor(part, 1);
                part += __shfl_xor(part, 2);
                part += __shfl_xor(part, 4);
                part += __shfl_xor(part, 8);
                if (l16 == 0) atomicAdd(&rs[rowg], part);
            }
        }
    } else {  // MODE == 3
        const float* rs = rsum + (z << 11);
        const float* cs = colsum + (z << 10);
#pragma unroll
        for (int mi = 0; mi < 4; ++mi) {
#pragma unroll
            for (int r = 0; r < 4; ++r) {
                int rowg = m0 + wm * 64 + mi * 16 + quad * 4 + r;
                float inv = 1.0f / (2048.0f + rs[rowg]);
#pragma unroll
                for (int ni = 0; ni < 4; ++ni) {
                    int colg = n0 + wn * 64 + ni * 16 + l16;
                    store1(Cb + (size_t)rowg * ldc + colg, (acc[mi][ni][r] + cs[colg]) * inv);
                }
            }
        }
    }
}

// ---------------------------------------------------------------------------
extern "C" void kernel_launch(void* const* d_in, const int* in_sizes, int n_in,
                              void* d_out, int out_size, void* d_ws, size_t ws_size,
                              hipStream_t stream) {
    const float* x     = (const float*)d_in[0];
    const float* Wq    = (const float*)d_in[1];
    const float* Wk    = (const float*)d_in[2];
    const float* Wv    = (const float*)d_in[3];
    const float* qmask = (const float*)d_in[4];
    float* out = (float*)d_out;

    const long nx = (long)BB * SS * DD;   // 8,388,608
    const long nw = (long)DD * DD;        // 1,048,576

    unsigned char* ws  = (unsigned char*)d_ws;
    unsigned char* x8  = ws;                          // x fp8         8.4 MB
    unsigned char* w8  = x8 + nx;                     // Wq,Wk,Wv fp8  3 MB
    unsigned char* qk8 = w8 + 3 * nw;                 // Q,K fp8       16.8 MB
    unsigned char* vt8 = qk8 + 2 * nx;                // V^T fp8 (B,D,S) 8.4 MB
    unsigned char* t8  = vt8 + nx;                    // T = 512(exp-1) fp8 (B,S,S) 16.8 MB
    float* xsum   = (float*)(t8 + (long)BB * SS * SS);// (B,D) 16 KB
    float* rs     = xsum + BB * DD;                   // (B,S) 32 KB  (Σt per row)
    float* colsum = rs + BB * SS;                     // (B,D) 16 KB

    // 0. zero the accumulators (xsum and rs are adjacent)
    hipMemsetAsync(xsum, 0, (size_t)(BB * DD + BB * SS) * sizeof(float), stream);

    // 1. conversions + exact colsum(V) path
    cvt_x_kernel<<<dim3((int)(nx / 8 / 256)), dim3(256), 0, stream>>>(x, x8, (int)(nx / 8));
    cvt_w_kernel<<<dim3((int)(3 * nw / 8 / 256)), dim3(256), 0, stream>>>(Wq, Wk, Wv, w8, (int)(nw / 8));
    xsum_kernel<<<dim3(16, 16), dim3(256), 0, stream>>>(x, xsum);
    colsumv_kernel<<<dim3(1024), dim3(256), 0, stream>>>(Wv, xsum, colsum);

    // 2. Q = x@Wq^T, K = x@Wk^T  (fp8 MX GEMM, z=2, fp8 out)  grid 8x32x2
    gemm_f8<0, f8_t><<<dim3(DD / 128, (BB * SS) / 256, 2), 512, 0, stream>>>(
        x8, w8, (f8_t*)qk8, BB * SS, DD, DD, 0, nw, nx, DD, 31, 0, nullptr, nullptr, nullptr);

    // 3. V^T = Wv @ x^T -> (B, D, S) fp8, col-batch-split store  grid 64x4
    gemm_f8<1, f8_t><<<dim3((BB * SS) / 128, DD / 256, 1), 512, 0, stream>>>(
        w8 + 2 * nw, x8, (f8_t*)vt8, DD, BB * SS, DD, 0, 0, 0, SS, 11, (long)DD * SS,
        nullptr, nullptr, nullptr);

    // 4. T = exp(mask*scores)-1 (x512, fp8) + row sums of t (atomics)  grid 16x8x4
    gemm_f8<2, f8_t><<<dim3(SS / 128, SS / 256, BB), 512, 0, stream>>>(
        qk8, qk8 + nx, (f8_t*)t8, SS, SS, DD, (long)SS * DD, (long)SS * DD, (long)SS * SS,
        SS, 31, 0, qmask, rs, nullptr);

    // 5. out = (T@V * 2^-9 + colsumV) / (2048 + rowsum_t), fp32  grid 8x8x4
    gemm_f8<3, float><<<dim3(DD / 128, SS / 256, BB), 512, 0, stream>>>(
        t8, vt8, out, SS, DD, SS, (long)SS * SS, (long)DD * SS, (long)SS * DD,
        DD, 31, 0, nullptr, rs, colsum);
}

// Round 3
// 214.502 us; speedup vs baseline: 1.0731x; 1.0316x over previous
//
#include <hip/hip_runtime.h>
#include <hip/hip_bf16.h>

// Problem constants (B=4, S=2048, D=1024, fp32 in/out)
#define BB 4
#define SS 2048
#define DD 1024

using f32x4  = __attribute__((ext_vector_type(4))) float;
using f32x16 = __attribute__((ext_vector_type(16))) float;
using i32x4  = __attribute__((ext_vector_type(4))) int;
using i32x8  = __attribute__((ext_vector_type(8))) int;

struct f8_t { unsigned char b; };

// async global->LDS, 16B per lane. LDS dest = wave-uniform base + lane*16.
__device__ __forceinline__ void gld16(const void* g, void* l) {
    __builtin_amdgcn_global_load_lds(
        (const __attribute__((address_space(1))) void*)(g),
        (__attribute__((address_space(3))) void*)(l),
        16, 0, 0);
}

__device__ __forceinline__ void store1(float* p, float v) { *p = v; }
__device__ __forceinline__ void store1(f8_t* p, float v)  {
    p->b = (unsigned char)(__builtin_amdgcn_cvt_pk_fp8_f32(v, v, 0, false) & 0xff);
}

// ---------------------------------------------------------------------------
// x: fp32 -> fp8(e4m3), 8 elems/thread
// ---------------------------------------------------------------------------
__global__ void cvt_x_kernel(const float* __restrict__ x, unsigned char* __restrict__ x8, int n8) {
    int i = blockIdx.x * blockDim.x + threadIdx.x;
    if (i >= n8) return;
    float4 a = ((const float4*)x)[2 * i];
    float4 b = ((const float4*)x)[2 * i + 1];
    int lo = __builtin_amdgcn_cvt_pk_fp8_f32(a.x, a.y, 0, false);
    lo     = __builtin_amdgcn_cvt_pk_fp8_f32(a.z, a.w, lo, true);
    int hi = __builtin_amdgcn_cvt_pk_fp8_f32(b.x, b.y, 0, false);
    hi     = __builtin_amdgcn_cvt_pk_fp8_f32(b.z, b.w, hi, true);
    ((int2*)x8)[i] = make_int2(lo, hi);
}

// Wq,Wk,Wv -> fp8 contiguous. n8 = nw/8.
__global__ void cvt_w_kernel(const float* __restrict__ Wq, const float* __restrict__ Wk,
                             const float* __restrict__ Wv, unsigned char* __restrict__ w8, int n8) {
    int i = blockIdx.x * blockDim.x + threadIdx.x;
    int seg = i / n8;            // wave-uniform (n8 % 256 == 0)
    int j = i - seg * n8;
    const float* src = (seg == 0) ? Wq : (seg == 1) ? Wk : Wv;
    float4 a = ((const float4*)src)[2 * j];
    float4 b = ((const float4*)src)[2 * j + 1];
    int lo = __builtin_amdgcn_cvt_pk_fp8_f32(a.x, a.y, 0, false);
    lo     = __builtin_amdgcn_cvt_pk_fp8_f32(a.z, a.w, lo, true);
    int hi = __builtin_amdgcn_cvt_pk_fp8_f32(b.x, b.y, 0, false);
    hi     = __builtin_amdgcn_cvt_pk_fp8_f32(b.z, b.w, hi, true);
    ((int2*)(w8 + (size_t)seg * n8 * 8))[j] = make_int2(lo, hi);
}

// ---------------------------------------------------------------------------
// xsum[b][d] = sum_s x[b][s][d]  (fp32, exact). atomics over s-chunks.
// ---------------------------------------------------------------------------
__global__ void xsum_kernel(const float* __restrict__ x, float* __restrict__ xsum) {
    int bd = blockIdx.x;
    int b  = bd >> 2, dc = bd & 3;
    int d  = dc * 256 + threadIdx.x;
    int s0 = blockIdx.y * 128;
    const float* p = x + ((size_t)b * SS + s0) * DD + d;
    float acc = 0.f;
    for (int i = 0; i < 128; ++i) acc += p[(size_t)i * DD];
    atomicAdd(&xsum[b * DD + d], acc);
}

// colsumV[b][c] = sum_d xsum[b][d] * Wv[c][d]   (one wave per output)
__global__ void colsumv_kernel(const float* __restrict__ Wv, const float* __restrict__ xsum,
                               float* __restrict__ colsum) {
    int idx  = blockIdx.x * 4 + (threadIdx.x >> 6);   // 0..4095
    int b    = idx >> 10, c = idx & 1023;
    int lane = threadIdx.x & 63;
    const float* wr = Wv + (size_t)c * DD;
    const float* xs = xsum + b * DD;
    float acc = 0.f;
#pragma unroll 4
    for (int d = lane; d < DD; d += 64) acc += wr[d] * xs[d];
#pragma unroll
    for (int off = 32; off; off >>= 1) acc += __shfl_xor(acc, off);
    if (lane == 0) colsum[idx] = acc;
}

// ---------------------------------------------------------------------------
// fp8 (e4m3) NT GEMM via MX-scaled MFMA 32x32x64 (half the instruction count
// and half the live frag registers of the 16x16x128 variant -> 4 blocks/CU).
// 128x128 tile, BK=128, 256 threads (4 waves, 2x2), per-wave 64x64 out as
// 2x2 of 32x32 frags. Single-buffered LDS, r0-proven loop:
//   stage 8x gld -> vmcnt(0) -> sync -> 2 K-steps x (4 ds_read-frag + 4 MFMA)
//   -> sync.   Latency hiding comes from 4 co-resident blocks (16 waves/CU).
// XOR-8 LDS swizzle on the staging source (T2).
// A/B frag layout (32x32x64 f8f6f4): row/col = lane&31, k-bytes =
//   (lane>>5)*32 + kstep*64. C/D: col = lane&31,
//   row = (reg&3) + 8*(reg>>2) + 4*(lane>>5), reg in [0,16).
// Epilogue modes:
//   0: plain store CT              (QK projection, fp8 out)
//   1: col-batch-split fp8 store   (V^T)
//   2: scores: t=exp(acc*qmask/32)-1; store fp8 512t; atomicAdd row sums of t
//   3: PV: out = (acc + colsumV[d]) / (2048 + rsum[q]), fp32; A-scale 2^-9
// ---------------------------------------------------------------------------
template <int MODE, typename CT>
__global__ __launch_bounds__(256, 4) void gemm_f8(
    const unsigned char* __restrict__ A, const unsigned char* __restrict__ B,
    CT* __restrict__ C, int M, int N, int K,
    long batchA, long batchB, long batchC,
    int ldc, int col_shift, long cstride,
    const float* __restrict__ qmask, float* __restrict__ rsum,
    const float* __restrict__ colsum) {
    constexpr int BM = 128, BN = 128, BK = 128;
    constexpr int SCALE_A = (MODE == 3) ? 118 : 127;   // 2^-9 un-scales T' = 512 t
    __shared__ __attribute__((aligned(16))) unsigned char As[BM * BK];  // 16 KB
    __shared__ __attribute__((aligned(16))) unsigned char Bs[BN * BK];  // 16 KB

    const int tid  = threadIdx.x;
    const int lane = tid & 63;
    const int wv   = tid >> 6;        // 0..3
    const int l31  = lane & 31;
    const int half = lane >> 5;       // 0..1
    const int hb   = half * 2;        // logical 16B-chunk base within a kstep
    const int wm   = wv >> 1;         // 0..1 : 64-row band
    const int wn   = wv & 1;          // 0..1 : 64-col band

    const int m0 = blockIdx.y * BM;
    const int n0 = blockIdx.x * BN;
    const long z = blockIdx.z;
    const unsigned char* Ab = A + z * batchA;
    const unsigned char* Bb = B + z * batchB;

    f32x16 acc[2][2] = {};

    // stage round j (j=0..3) of a 128x128-byte tile for K-offset kt.
    // Source address carries the XOR-8 swizzle; LDS dest is linear
    // (global_load_lds writes wave-uniform base + lane*16).
#define STAGE(dst, src, kt, j) do {                                           \
        int slot_ = (j) * 256 + tid;                                          \
        int r_ = slot_ >> 3;                                                  \
        int c_ = (slot_ & 7) ^ (r_ & 7);                                      \
        gld16((src) + (size_t)r_ * K + ((kt) + c_ * 16),                      \
              (dst) + (size_t)((j) * 256 + wv * 64) * 16);                    \
    } while (0)
    // read one 32x64 fragment (32 B/lane, two swizzled 16B chunks) for kstep s
#define RDFRAG(f, base, rr, s) do {                                           \
        int r_ = (rr);                                                        \
        int c0_ = (s) * 4 + hb;                                               \
        const unsigned char* rp_ = (base) + r_ * 128;                         \
        i32x4 q0_ = *(const i32x4*)(rp_ + ((c0_ ^ (r_ & 7)) * 16));           \
        i32x4 q1_ = *(const i32x4*)(rp_ + (((c0_ + 1) ^ (r_ & 7)) * 16));     \
        f[0]=q0_[0]; f[1]=q0_[1]; f[2]=q0_[2]; f[3]=q0_[3];                   \
        f[4]=q1_[0]; f[5]=q1_[1]; f[6]=q1_[2]; f[7]=q1_[3];                   \
    } while (0)
#define MFMA(d, a, b) \
        d = __builtin_amdgcn_mfma_scale_f32_32x32x64_f8f6f4(a, b, d, 0, 0, 0, SCALE_A, 0, 127)

    for (int kt = 0; kt < K; kt += BK) {
        STAGE(As, Ab + (size_t)m0 * K, kt, 0); STAGE(As, Ab + (size_t)m0 * K, kt, 1);
        STAGE(As, Ab + (size_t)m0 * K, kt, 2); STAGE(As, Ab + (size_t)m0 * K, kt, 3);
        STAGE(Bs, Bb + (size_t)n0 * K, kt, 0); STAGE(Bs, Bb + (size_t)n0 * K, kt, 1);
        STAGE(Bs, Bb + (size_t)n0 * K, kt, 2); STAGE(Bs, Bb + (size_t)n0 * K, kt, 3);
        asm volatile("s_waitcnt vmcnt(0)" ::: "memory");
        __syncthreads();

#pragma unroll
        for (int s = 0; s < 2; ++s) {
            i32x8 a0, a1, b0, b1;
            RDFRAG(a0, As, wm * 64 +  0 + l31, s);
            RDFRAG(a1, As, wm * 64 + 32 + l31, s);
            RDFRAG(b0, Bs, wn * 64 +  0 + l31, s);
            RDFRAG(b1, Bs, wn * 64 + 32 + l31, s);
            MFMA(acc[0][0], a0, b0); MFMA(acc[0][1], a0, b1);
            MFMA(acc[1][0], a1, b0); MFMA(acc[1][1], a1, b1);
        }
        __syncthreads();
    }
#undef STAGE
#undef RDFRAG
#undef MFMA

    // ---- epilogue (C/D: col=lane&31, row=(reg&3)+8*(reg>>2)+4*half) --------
    CT* Cb = C + z * batchC;

    if constexpr (MODE == 0) {
#pragma unroll
        for (int mi = 0; mi < 2; ++mi)
#pragma unroll
            for (int ni = 0; ni < 2; ++ni) {
                int colg = n0 + wn * 64 + ni * 32 + l31;
#pragma unroll
                for (int reg = 0; reg < 16; ++reg) {
                    int rowg = m0 + wm * 64 + mi * 32 + (reg & 3) + 8 * (reg >> 2) + 4 * half;
                    store1(Cb + (size_t)rowg * ldc + colg, acc[mi][ni][reg]);
                }
            }
    } else if constexpr (MODE == 1) {
#pragma unroll
        for (int mi = 0; mi < 2; ++mi)
#pragma unroll
            for (int ni = 0; ni < 2; ++ni) {
                int colg = n0 + wn * 64 + ni * 32 + l31;
                int cb   = colg >> col_shift;
                int ccol = colg - (cb << col_shift);
#pragma unroll
                for (int reg = 0; reg < 16; ++reg) {
                    int rowg = m0 + wm * 64 + mi * 32 + (reg & 3) + 8 * (reg >> 2) + 4 * half;
                    store1(Cb + (long)cb * cstride + (size_t)rowg * ldc + ccol, acc[mi][ni][reg]);
                }
            }
    } else if constexpr (MODE == 2) {
        const float* qm = qmask + (z << 11);
        float* rs = rsum + (z << 11);
#pragma unroll
        for (int mi = 0; mi < 2; ++mi) {
#pragma unroll
            for (int reg = 0; reg < 16; ++reg) {
                int rowg = m0 + wm * 64 + mi * 32 + (reg & 3) + 8 * (reg >> 2) + 4 * half;
                float fac = qm[rowg] * 0.03125f;     // q_mask / sqrt(1024)
                float part = 0.f;
#pragma unroll
                for (int ni = 0; ni < 2; ++ni) {
                    int colg = n0 + wn * 64 + ni * 32 + l31;
                    float t = __expf(acc[mi][ni][reg] * fac) - 1.0f;
                    part += t;
                    store1(Cb + (size_t)rowg * ldc + colg, t * 512.0f);
                }
                // reduce over the 32 lanes of this half (they share rowg)
                part += __shfl_xor(part, 1);
                part += __shfl_xor(part, 2);
                part += __shfl_xor(part, 4);
                part += __shfl_xor(part, 8);
                part += __shfl_xor(part, 16);
                if (l31 == 0) atomicAdd(&rs[rowg], part);
            }
        }
    } else {  // MODE == 3
        const float* rs = rsum + (z << 11);
        const float* cs = colsum + (z << 10);
#pragma unroll
        for (int mi = 0; mi < 2; ++mi) {
#pragma unroll
            for (int reg = 0; reg < 16; ++reg) {
                int rowg = m0 + wm * 64 + mi * 32 + (reg & 3) + 8 * (reg >> 2) + 4 * half;
                float inv = 1.0f / (2048.0f + rs[rowg]);
#pragma unroll
                for (int ni = 0; ni < 2; ++ni) {
                    int colg = n0 + wn * 64 + ni * 32 + l31;
                    store1(Cb + (size_t)rowg * ldc + colg, (acc[mi][ni][reg] + cs[colg]) * inv);
                }
            }
        }
    }
}

// ---------------------------------------------------------------------------
extern "C" void kernel_launch(void* const* d_in, const int* in_sizes, int n_in,
                              void* d_out, int out_size, void* d_ws, size_t ws_size,
                              hipStream_t stream) {
    const float* x     = (const float*)d_in[0];
    const float* Wq    = (const float*)d_in[1];
    const float* Wk    = (const float*)d_in[2];
    const float* Wv    = (const float*)d_in[3];
    const float* qmask = (const float*)d_in[4];
    float* out = (float*)d_out;

    const long nx = (long)BB * SS * DD;   // 8,388,608
    const long nw = (long)DD * DD;        // 1,048,576

    unsigned char* ws  = (unsigned char*)d_ws;
    unsigned char* x8  = ws;                          // x fp8         8.4 MB
    unsigned char* w8  = x8 + nx;                     // Wq,Wk,Wv fp8  3 MB
    unsigned char* qk8 = w8 + 3 * nw;                 // Q,K fp8       16.8 MB
    unsigned char* vt8 = qk8 + 2 * nx;                // V^T fp8 (B,D,S) 8.4 MB
    unsigned char* t8  = vt8 + nx;                    // T = 512(exp-1) fp8 (B,S,S) 16.8 MB
    float* xsum   = (float*)(t8 + (long)BB * SS * SS);// (B,D) 16 KB
    float* rs     = xsum + BB * DD;                   // (B,S) 32 KB  (Σt per row)
    float* colsum = rs + BB * SS;                     // (B,D) 16 KB

    // 0. zero the accumulators (xsum and rs are adjacent)
    hipMemsetAsync(xsum, 0, (size_t)(BB * DD + BB * SS) * sizeof(float), stream);

    // 1. conversions + exact colsum(V) path
    cvt_x_kernel<<<dim3((int)(nx / 8 / 256)), dim3(256), 0, stream>>>(x, x8, (int)(nx / 8));
    cvt_w_kernel<<<dim3((int)(3 * nw / 8 / 256)), dim3(256), 0, stream>>>(Wq, Wk, Wv, w8, (int)(nw / 8));
    xsum_kernel<<<dim3(16, 16), dim3(256), 0, stream>>>(x, xsum);
    colsumv_kernel<<<dim3(1024), dim3(256), 0, stream>>>(Wv, xsum, colsum);

    // 2. Q = x@Wq^T, K = x@Wk^T  (fp8 MX GEMM, z=2, fp8 out)
    gemm_f8<0, f8_t><<<dim3(DD / 128, (BB * SS) / 128, 2), 256, 0, stream>>>(
        x8, w8, (f8_t*)qk8, BB * SS, DD, DD, 0, nw, nx, DD, 31, 0, nullptr, nullptr, nullptr);

    // 3. V^T = Wv @ x^T -> (B, D, S) fp8, col-batch-split store
    gemm_f8<1, f8_t><<<dim3((BB * SS) / 128, DD / 128, 1), 256, 0, stream>>>(
        w8 + 2 * nw, x8, (f8_t*)vt8, DD, BB * SS, DD, 0, 0, 0, SS, 11, (long)DD * SS,
        nullptr, nullptr, nullptr);

    // 4. T = exp(mask*scores)-1 (x512, fp8) + row sums of t (atomics)
    gemm_f8<2, f8_t><<<dim3(SS / 128, SS / 128, BB), 256, 0, stream>>>(
        qk8, qk8 + nx, (f8_t*)t8, SS, SS, DD, (long)SS * DD, (long)SS * DD, (long)SS * SS,
        SS, 31, 0, qmask, rs, nullptr);

    // 5. out = (T@V * 2^-9 + colsumV) / (2048 + rowsum_t), fp32
    gemm_f8<3, float><<<dim3(DD / 128, SS / 128, BB), 256, 0, stream>>>(
        t8, vt8, out, SS, DD, SS, (long)SS * SS, (long)DD * SS, (long)SS * DD,
        DD, 31, 0, nullptr, rs, colsum);
}

// Round 5
// 212.649 us; speedup vs baseline: 1.0824x; 1.0087x over previous
//
#include <hip/hip_runtime.h>
#include <hip/hip_bf16.h>

// Problem constants (B=4, S=2048, D=1024, fp32 in/out)
#define BB 4
#define SS 2048
#define DD 1024

using f32x4  = __attribute__((ext_vector_type(4))) float;
using f32x16 = __attribute__((ext_vector_type(16))) float;
using i32x4  = __attribute__((ext_vector_type(4))) int;
using i32x8  = __attribute__((ext_vector_type(8))) int;

struct f8_t { unsigned char b; };

// async global->LDS, 16B per lane. LDS dest = wave-uniform base + lane*16.
__device__ __forceinline__ void gld16(const void* g, void* l) {
    __builtin_amdgcn_global_load_lds(
        (const __attribute__((address_space(1))) void*)(g),
        (__attribute__((address_space(3))) void*)(l),
        16, 0, 0);
}

__device__ __forceinline__ void store1(float* p, float v) { *p = v; }
__device__ __forceinline__ void store1(f8_t* p, float v)  {
    p->b = (unsigned char)(__builtin_amdgcn_cvt_pk_fp8_f32(v, v, 0, false) & 0xff);
}

// ---------------------------------------------------------------------------
// x: fp32 -> fp8(e4m3), 8 elems/thread
// ---------------------------------------------------------------------------
__global__ void cvt_x_kernel(const float* __restrict__ x, unsigned char* __restrict__ x8, int n8) {
    int i = blockIdx.x * blockDim.x + threadIdx.x;
    if (i >= n8) return;
    float4 a = ((const float4*)x)[2 * i];
    float4 b = ((const float4*)x)[2 * i + 1];
    int lo = __builtin_amdgcn_cvt_pk_fp8_f32(a.x, a.y, 0, false);
    lo     = __builtin_amdgcn_cvt_pk_fp8_f32(a.z, a.w, lo, true);
    int hi = __builtin_amdgcn_cvt_pk_fp8_f32(b.x, b.y, 0, false);
    hi     = __builtin_amdgcn_cvt_pk_fp8_f32(b.z, b.w, hi, true);
    ((int2*)x8)[i] = make_int2(lo, hi);
}

// Wq,Wk,Wv -> fp8 contiguous. n8 = nw/8.
__global__ void cvt_w_kernel(const float* __restrict__ Wq, const float* __restrict__ Wk,
                             const float* __restrict__ Wv, unsigned char* __restrict__ w8, int n8) {
    int i = blockIdx.x * blockDim.x + threadIdx.x;
    int seg = i / n8;            // wave-uniform (n8 % 256 == 0)
    int j = i - seg * n8;
    const float* src = (seg == 0) ? Wq : (seg == 1) ? Wk : Wv;
    float4 a = ((const float4*)src)[2 * j];
    float4 b = ((const float4*)src)[2 * j + 1];
    int lo = __builtin_amdgcn_cvt_pk_fp8_f32(a.x, a.y, 0, false);
    lo     = __builtin_amdgcn_cvt_pk_fp8_f32(a.z, a.w, lo, true);
    int hi = __builtin_amdgcn_cvt_pk_fp8_f32(b.x, b.y, 0, false);
    hi     = __builtin_amdgcn_cvt_pk_fp8_f32(b.z, b.w, hi, true);
    ((int2*)(w8 + (size_t)seg * n8 * 8))[j] = make_int2(lo, hi);
}

// ---------------------------------------------------------------------------
// xsum[b][d] = sum_s x[b][s][d]  (fp32, EXACT -- the output's leading term
// colsumV/2048 flows through this; it must not see fp8 noise).
// ---------------------------------------------------------------------------
__global__ void xsum_kernel(const float* __restrict__ x, float* __restrict__ xsum) {
    int bd = blockIdx.x;
    int b  = bd >> 2, dc = bd & 3;
    int d  = dc * 256 + threadIdx.x;
    int s0 = blockIdx.y * 128;
    const float* p = x + ((size_t)b * SS + s0) * DD + d;
    float acc = 0.f;
    for (int i = 0; i < 128; ++i) acc += p[(size_t)i * DD];
    atomicAdd(&xsum[b * DD + d], acc);
}

// colsumV[b][c] = sum_d xsum[b][d] * Wv[c][d]   (one wave per output, exact)
__global__ void colsumv_kernel(const float* __restrict__ Wv, const float* __restrict__ xsum,
                               float* __restrict__ colsum) {
    int idx  = blockIdx.x * 4 + (threadIdx.x >> 6);   // 0..4095
    int b    = idx >> 10, c = idx & 1023;
    int lane = threadIdx.x & 63;
    const float* wr = Wv + (size_t)c * DD;
    const float* xs = xsum + b * DD;
    float acc = 0.f;
#pragma unroll 4
    for (int d = lane; d < DD; d += 64) acc += wr[d] * xs[d];
#pragma unroll
    for (int off = 32; off; off >>= 1) acc += __shfl_xor(acc, off);
    if (lane == 0) colsum[idx] = acc;
}

// ---------------------------------------------------------------------------
// SMALL GEMM (128x128 tile, 32x32x64 MX MFMA) -- r3-proven loop.
// Used for the narrow shapes (mode 1: V^T, mode 3: PV) where a 256^2 grid
// would leave half the GPU idle.
// ---------------------------------------------------------------------------
template <int MODE, typename CT>
__global__ __launch_bounds__(256, 4) void gemm_f8(
    const unsigned char* __restrict__ A, const unsigned char* __restrict__ B,
    CT* __restrict__ C, int M, int N, int K,
    long batchA, long batchB, long batchC,
    int ldc, int col_shift, long cstride,
    const float* __restrict__ qmask, float* __restrict__ rsum,
    const float* __restrict__ colsum) {
    constexpr int BM = 128, BN = 128, BK = 128;
    constexpr int SCALE_A = (MODE == 3) ? 118 : 127;   // 2^-9 un-scales T' = 512 t
    __shared__ __attribute__((aligned(16))) unsigned char As[BM * BK];  // 16 KB
    __shared__ __attribute__((aligned(16))) unsigned char Bs[BN * BK];  // 16 KB

    const int tid  = threadIdx.x;
    const int lane = tid & 63;
    const int wv   = tid >> 6;        // 0..3
    const int l31  = lane & 31;
    const int half = lane >> 5;       // 0..1
    const int hb   = half * 2;        // logical 16B-chunk base within a kstep
    const int wm   = wv >> 1;         // 0..1 : 64-row band
    const int wn   = wv & 1;          // 0..1 : 64-col band

    const int m0 = blockIdx.y * BM;
    const int n0 = blockIdx.x * BN;
    const long z = blockIdx.z;
    const unsigned char* Ab = A + z * batchA;
    const unsigned char* Bb = B + z * batchB;

    f32x16 acc[2][2] = {};

#define STAGE(dst, src, kt, j) do {                                           \
        int slot_ = (j) * 256 + tid;                                          \
        int r_ = slot_ >> 3;                                                  \
        int c_ = (slot_ & 7) ^ (r_ & 7);                                      \
        gld16((src) + (size_t)r_ * K + ((kt) + c_ * 16),                      \
              (dst) + (size_t)((j) * 256 + wv * 64) * 16);                    \
    } while (0)
#define RDFRAG(f, base, rr, s) do {                                           \
        int r_ = (rr);                                                        \
        int c0_ = (s) * 4 + hb;                                               \
        const unsigned char* rp_ = (base) + r_ * 128;                         \
        i32x4 q0_ = *(const i32x4*)(rp_ + ((c0_ ^ (r_ & 7)) * 16));           \
        i32x4 q1_ = *(const i32x4*)(rp_ + (((c0_ + 1) ^ (r_ & 7)) * 16));     \
        f[0]=q0_[0]; f[1]=q0_[1]; f[2]=q0_[2]; f[3]=q0_[3];                   \
        f[4]=q1_[0]; f[5]=q1_[1]; f[6]=q1_[2]; f[7]=q1_[3];                   \
    } while (0)
#define MFMA(d, a, b) \
        d = __builtin_amdgcn_mfma_scale_f32_32x32x64_f8f6f4(a, b, d, 0, 0, 0, SCALE_A, 0, 127)

    for (int kt = 0; kt < K; kt += BK) {
        STAGE(As, Ab + (size_t)m0 * K, kt, 0); STAGE(As, Ab + (size_t)m0 * K, kt, 1);
        STAGE(As, Ab + (size_t)m0 * K, kt, 2); STAGE(As, Ab + (size_t)m0 * K, kt, 3);
        STAGE(Bs, Bb + (size_t)n0 * K, kt, 0); STAGE(Bs, Bb + (size_t)n0 * K, kt, 1);
        STAGE(Bs, Bb + (size_t)n0 * K, kt, 2); STAGE(Bs, Bb + (size_t)n0 * K, kt, 3);
        asm volatile("s_waitcnt vmcnt(0)" ::: "memory");
        __syncthreads();

#pragma unroll
        for (int s = 0; s < 2; ++s) {
            i32x8 a0, a1, b0, b1;
            RDFRAG(a0, As, wm * 64 +  0 + l31, s);
            RDFRAG(a1, As, wm * 64 + 32 + l31, s);
            RDFRAG(b0, Bs, wn * 64 +  0 + l31, s);
            RDFRAG(b1, Bs, wn * 64 + 32 + l31, s);
            MFMA(acc[0][0], a0, b0); MFMA(acc[0][1], a0, b1);
            MFMA(acc[1][0], a1, b0); MFMA(acc[1][1], a1, b1);
        }
        __syncthreads();
    }
#undef STAGE
#undef RDFRAG
#undef MFMA

    // ---- epilogue (C/D: col=lane&31, row=(reg&3)+8*(reg>>2)+4*half) --------
    CT* Cb = C + z * batchC;

    if constexpr (MODE == 1) {
#pragma unroll
        for (int mi = 0; mi < 2; ++mi)
#pragma unroll
            for (int ni = 0; ni < 2; ++ni) {
                int colg = n0 + wn * 64 + ni * 32 + l31;
                int cb   = colg >> col_shift;
                int ccol = colg - (cb << col_shift);
#pragma unroll
                for (int reg = 0; reg < 16; ++reg) {
                    int rowg = m0 + wm * 64 + mi * 32 + (reg & 3) + 8 * (reg >> 2) + 4 * half;
                    store1(Cb + (long)cb * cstride + (size_t)rowg * ldc + ccol, acc[mi][ni][reg]);
                }
            }
    } else {  // MODE == 3
        const float* rs = rsum + (z << 11);
        const float* cs = colsum + (z << 10);
#pragma unroll
        for (int mi = 0; mi < 2; ++mi) {
#pragma unroll
            for (int reg = 0; reg < 16; ++reg) {
                int rowg = m0 + wm * 64 + mi * 32 + (reg & 3) + 8 * (reg >> 2) + 4 * half;
                float inv = 1.0f / (2048.0f + rs[rowg]);
#pragma unroll
                for (int ni = 0; ni < 2; ++ni) {
                    int colg = n0 + wn * 64 + ni * 32 + l31;
                    store1(Cb + (size_t)rowg * ldc + colg, (acc[mi][ni][reg] + cs[colg]) * inv);
                }
            }
        }
    }
}

// ---------------------------------------------------------------------------
// BIG GEMM: 256x256 tile, BK=128, 16x16x128 MX MFMA, 512 thr (8 waves, 2Mx4N,
// per-wave 128x64 out -> 0.75 ds_read_b128 per MFMA). m201-style schedule:
// double-buffered LDS, 4 fine phases per K-tile, each phase =
//   { ds_read frag subtile || issue 2-3 global_load_lds of tile t+1
//     -> s_barrier -> lgkmcnt(0) -> setprio(1) 8xMFMA setprio(0) -> s_barrier }
// Staging is FRONT-loaded into phases 0-2, so the tile-boundary vmcnt(0)
// drains loads aged >= 1 full phase -- near-free in steady state.
// Grids stay >= 256 blocks: used for mode 0 (QK proj) and mode 2 (scores).
// ---------------------------------------------------------------------------
template <int MODE, typename CT>
__global__ __launch_bounds__(512, 2) void gemm_f8_big(
    const unsigned char* __restrict__ A, const unsigned char* __restrict__ B,
    CT* __restrict__ C, int K,
    long batchA, long batchB, long batchC, int ldc,
    const float* __restrict__ qmask, float* __restrict__ rsum) {
    constexpr int BM = 256, BN = 256, BK = 128;
    __shared__ __attribute__((aligned(16))) unsigned char As[2][BM * BK];  // 64 KB
    __shared__ __attribute__((aligned(16))) unsigned char Bs[2][BN * BK];  // 64 KB

    const int tid  = threadIdx.x;
    const int lane = tid & 63;
    const int wv   = tid >> 6;        // 0..7
    const int l16  = lane & 15;
    const int quad = lane >> 4;
    const int wm   = wv >> 2;         // 0..1 : 128-row band
    const int wn   = wv & 3;          // 0..3 : 64-col band

    const int m0 = blockIdx.y * BM;
    const int n0 = blockIdx.x * BN;
    const long z = blockIdx.z;
    const unsigned char* Ab = A + z * batchA;
    const unsigned char* Bb = B + z * batchB;

    const int cbase = 2 * quad;       // chunk pair base for frag reads

    f32x4 acc[8][4] = {};

#define STA(buf, kt, j) do {                                                  \
        int slot_ = (j) * 512 + tid;                                          \
        int r_ = slot_ >> 3;                                                  \
        int c_ = (slot_ & 7) ^ (r_ & 7);                                      \
        gld16(Ab + (size_t)(m0 + r_) * K + ((kt) + c_ * 16),                  \
              &As[buf][((j) * 512 + wv * 64) * 16]);                          \
    } while (0)
#define STB(buf, kt, j) do {                                                  \
        int slot_ = (j) * 512 + tid;                                          \
        int r_ = slot_ >> 3;                                                  \
        int c_ = (slot_ & 7) ^ (r_ & 7);                                      \
        gld16(Bb + (size_t)(n0 + r_) * K + ((kt) + c_ * 16),                  \
              &Bs[buf][((j) * 512 + wv * 64) * 16]);                          \
    } while (0)
#define RD(f, base, r) do {                                                   \
        int cc_ = cbase ^ ((r) & 7);                                          \
        i32x4 p0_ = *(const i32x4*)((base) + (r) * 128 + cc_ * 16);           \
        i32x4 p1_ = *(const i32x4*)((base) + (r) * 128 + (cc_ ^ 1) * 16);     \
        f[0]=p0_[0]; f[1]=p0_[1]; f[2]=p0_[2]; f[3]=p0_[3];                   \
        f[4]=p1_[0]; f[5]=p1_[1]; f[6]=p1_[2]; f[7]=p1_[3];                   \
    } while (0)
#define MM(d, a, b) \
        d = __builtin_amdgcn_mfma_scale_f32_16x16x128_f8f6f4(a, b, d, 0, 0, 0, 127, 0, 127)
#define LGKM0() do { \
        asm volatile("s_waitcnt lgkmcnt(0)" ::: "memory"); \
        __builtin_amdgcn_sched_barrier(0); } while (0)

    // ---- prologue: stage tile 0 into buffer 0, full drain once ------------
    STA(0, 0, 0); STA(0, 0, 1); STA(0, 0, 2); STA(0, 0, 3);
    STB(0, 0, 0); STB(0, 0, 1); STB(0, 0, 2); STB(0, 0, 3);
    asm volatile("s_waitcnt vmcnt(0)" ::: "memory");
    __builtin_amdgcn_s_barrier();

    const int NT = K / BK;
    for (int t = 0; t < NT; ++t) {
        const int cur = t & 1;
        const int nxt = cur ^ 1;
        const unsigned char* Ac = &As[cur][0];
        const unsigned char* Bc = &Bs[cur][0];
        const int ktn = (t + 1) * BK;
        const bool pf = (t + 1 < NT);

        i32x8 b0, b1, b2, b3, aA, aB;

        // ---- phase 0: B frags + A rows 0,16; stage A0-A2; mfma mi=0,1 -----
        RD(b0, Bc, wn * 64 +  0 + l16);
        RD(b1, Bc, wn * 64 + 16 + l16);
        RD(b2, Bc, wn * 64 + 32 + l16);
        RD(b3, Bc, wn * 64 + 48 + l16);
        RD(aA, Ac, wm * 128 +  0 + l16);
        RD(aB, Ac, wm * 128 + 16 + l16);
        if (pf) { STA(nxt, ktn, 0); STA(nxt, ktn, 1); STA(nxt, ktn, 2); }
        __builtin_amdgcn_s_barrier();
        LGKM0();
        __builtin_amdgcn_s_setprio(1);
        MM(acc[0][0], aA, b0); MM(acc[0][1], aA, b1); MM(acc[0][2], aA, b2); MM(acc[0][3], aA, b3);
        MM(acc[1][0], aB, b0); MM(acc[1][1], aB, b1); MM(acc[1][2], aB, b2); MM(acc[1][3], aB, b3);
        __builtin_amdgcn_s_setprio(0);
        __builtin_amdgcn_s_barrier();

        // ---- phase 1: A rows 32,48; stage A3,B0,B1; mfma mi=2,3 -----------
        RD(aA, Ac, wm * 128 + 32 + l16);
        RD(aB, Ac, wm * 128 + 48 + l16);
        if (pf) { STA(nxt, ktn, 3); STB(nxt, ktn, 0); STB(nxt, ktn, 1); }
        __builtin_amdgcn_s_barrier();
        LGKM0();
        __builtin_amdgcn_s_setprio(1);
        MM(acc[2][0], aA, b0); MM(acc[2][1], aA, b1); MM(acc[2][2], aA, b2); MM(acc[2][3], aA, b3);
        MM(acc[3][0], aB, b0); MM(acc[3][1], aB, b1); MM(acc[3][2], aB, b2); MM(acc[3][3], aB, b3);
        __builtin_amdgcn_s_setprio(0);
        __builtin_amdgcn_s_barrier();

        // ---- phase 2: A rows 64,80; stage B2,B3; mfma mi=4,5 --------------
        RD(aA, Ac, wm * 128 + 64 + l16);
        RD(aB, Ac, wm * 128 + 80 + l16);
        if (pf) { STB(nxt, ktn, 2); STB(nxt, ktn, 3); }
        __builtin_amdgcn_s_barrier();
        LGKM0();
        __builtin_amdgcn_s_setprio(1);
        MM(acc[4][0], aA, b0); MM(acc[4][1], aA, b1); MM(acc[4][2], aA, b2); MM(acc[4][3], aA, b3);
        MM(acc[5][0], aB, b0); MM(acc[5][1], aB, b1); MM(acc[5][2], aB, b2); MM(acc[5][3], aB, b3);
        __builtin_amdgcn_s_setprio(0);
        __builtin_amdgcn_s_barrier();

        // ---- phase 3: A rows 96,112; mfma mi=6,7; aged boundary drain -----
        RD(aA, Ac, wm * 128 +  96 + l16);
        RD(aB, Ac, wm * 128 + 112 + l16);
        __builtin_amdgcn_s_barrier();
        LGKM0();
        __builtin_amdgcn_s_setprio(1);
        MM(acc[6][0], aA, b0); MM(acc[6][1], aA, b1); MM(acc[6][2], aA, b2); MM(acc[6][3], aA, b3);
        MM(acc[7][0], aB, b0); MM(acc[7][1], aB, b1); MM(acc[7][2], aB, b2); MM(acc[7][3], aB, b3);
        __builtin_amdgcn_s_setprio(0);
        // youngest in-flight stage (STB3) was issued one full phase ago.
        asm volatile("s_waitcnt vmcnt(0)" ::: "memory");
        __builtin_amdgcn_s_barrier();
    }
#undef STA
#undef STB
#undef RD
#undef MM
#undef LGKM0

    // ---- epilogue (C/D layout: col=lane&15, row=quad*4+reg) ---------------
    CT* Cb = C + z * batchC;

    if constexpr (MODE == 0) {
#pragma unroll
        for (int mi = 0; mi < 8; ++mi)
#pragma unroll
            for (int ni = 0; ni < 4; ++ni) {
                int colg = n0 + wn * 64 + ni * 16 + l16;
#pragma unroll
                for (int r = 0; r < 4; ++r) {
                    int rowg = m0 + wm * 128 + mi * 16 + quad * 4 + r;
                    store1(Cb + (size_t)rowg * ldc + colg, acc[mi][ni][r]);
                }
            }
    } else {  // MODE == 2
        const float* qm = qmask + (z << 11);
        float* rs = rsum + (z << 11);
#pragma unroll
        for (int mi = 0; mi < 8; ++mi) {
#pragma unroll
            for (int r = 0; r < 4; ++r) {
                int rowg = m0 + wm * 128 + mi * 16 + quad * 4 + r;
                float fac = qm[rowg] * 0.03125f;     // q_mask / sqrt(1024)
                float part = 0.f;
#pragma unroll
                for (int ni = 0; ni < 4; ++ni) {
                    int colg = n0 + wn * 64 + ni * 16 + l16;
                    float tt = __expf(acc[mi][ni][r] * fac) - 1.0f;
                    part += tt;
                    store1(Cb + (size_t)rowg * ldc + colg, tt * 512.0f);
                }
                part += __shfl_xor(part, 1);
                part += __shfl_xor(part, 2);
                part += __shfl_xor(part, 4);
                part += __shfl_xor(part, 8);
                if (l16 == 0) atomicAdd(&rs[rowg], part);
            }
        }
    }
}

// ---------------------------------------------------------------------------
extern "C" void kernel_launch(void* const* d_in, const int* in_sizes, int n_in,
                              void* d_out, int out_size, void* d_ws, size_t ws_size,
                              hipStream_t stream) {
    const float* x     = (const float*)d_in[0];
    const float* Wq    = (const float*)d_in[1];
    const float* Wk    = (const float*)d_in[2];
    const float* Wv    = (const float*)d_in[3];
    const float* qmask = (const float*)d_in[4];
    float* out = (float*)d_out;

    const long nx = (long)BB * SS * DD;   // 8,388,608
    const long nw = (long)DD * DD;        // 1,048,576

    unsigned char* ws  = (unsigned char*)d_ws;
    unsigned char* x8  = ws;                          // x fp8         8.4 MB
    unsigned char* w8  = x8 + nx;                     // Wq,Wk,Wv fp8  3 MB
    unsigned char* qk8 = w8 + 3 * nw;                 // Q,K fp8       16.8 MB
    unsigned char* vt8 = qk8 + 2 * nx;                // V^T fp8 (B,D,S) 8.4 MB
    unsigned char* t8  = vt8 + nx;                    // T = 512(exp-1) fp8 (B,S,S) 16.8 MB
    float* xsum   = (float*)(t8 + (long)BB * SS * SS);// (B,D) 16 KB
    float* rs     = xsum + BB * DD;                   // (B,S) 32 KB  (Σt per row)
    float* colsum = rs + BB * SS;                     // (B,D) 16 KB  (exact)

    // 0. zero the atomic accumulators (xsum and rs are adjacent)
    hipMemsetAsync(xsum, 0, (size_t)(BB * DD + BB * SS) * sizeof(float), stream);

    // 1. conversions + exact colsum(V) path (fp32 -- the output's leading term)
    cvt_x_kernel<<<dim3((int)(nx / 8 / 256)), dim3(256), 0, stream>>>(x, x8, (int)(nx / 8));
    cvt_w_kernel<<<dim3((int)(3 * nw / 8 / 256)), dim3(256), 0, stream>>>(Wq, Wk, Wv, w8, (int)(nw / 8));
    xsum_kernel<<<dim3(16, 16), dim3(256), 0, stream>>>(x, xsum);
    colsumv_kernel<<<dim3(1024), dim3(256), 0, stream>>>(Wv, xsum, colsum);

    // 2. Q = x@Wq^T, K = x@Wk^T  (256^2 big kernel, z=2, fp8 out)  grid 4x32x2
    gemm_f8_big<0, f8_t><<<dim3(DD / 256, (BB * SS) / 256, 2), 512, 0, stream>>>(
        x8, w8, (f8_t*)qk8, DD, 0, nw, nx, DD, nullptr, nullptr);

    // 3. V^T = Wv @ x^T -> (B, D, S) fp8, col-batch-split store
    gemm_f8<1, f8_t><<<dim3((BB * SS) / 128, DD / 128, 1), 256, 0, stream>>>(
        w8 + 2 * nw, x8, (f8_t*)vt8, DD, BB * SS, DD, 0, 0, 0, SS, 11, (long)DD * SS,
        nullptr, nullptr, nullptr);

    // 4. T = exp(mask*scores)-1 (x512, fp8) + row sums of t (atomics)  grid 8x8x4
    gemm_f8_big<2, f8_t><<<dim3(SS / 256, SS / 256, BB), 512, 0, stream>>>(
        qk8, qk8 + nx, (f8_t*)t8, DD, (long)SS * DD, (long)SS * DD, (long)SS * SS,
        SS, qmask, rs);

    // 5. out = (T@V * 2^-9 + colsumV) / (2048 + rowsum_t), fp32
    gemm_f8<3, float><<<dim3(DD / 128, SS / 128, BB), 256, 0, stream>>>(
        t8, vt8, out, SS, DD, SS, (long)SS * SS, (long)DD * SS, (long)SS * DD,
        DD, 31, 0, nullptr, rs, colsum);
}